// Round 1
// baseline (406.507 us; speedup 1.0000x reference)
//
#include <hip/hip_runtime.h>
#include <hip/hip_bf16.h>

typedef __bf16 bf16x8 __attribute__((ext_vector_type(8)));
typedef __bf16 bf16x4 __attribute__((ext_vector_type(4)));
typedef float  f32x4  __attribute__((ext_vector_type(4)));

#define N_IN 1024
#define BM   64
#define NTHR 512

// Convert B (fp32, 1024x1024) to bf16 in workspace.
__global__ void convB_kernel(const float* __restrict__ B, __bf16* __restrict__ Bb) {
    int i = blockIdx.x * blockDim.x + threadIdx.x;   // 0..262143 (float4 units)
    f32x4 v = ((const f32x4*)B)[i];
    bf16x4 o;
    o[0] = (__bf16)v[0]; o[1] = (__bf16)v[1]; o[2] = (__bf16)v[2]; o[3] = (__bf16)v[3];
    ((bf16x4*)Bb)[i] = o;
}

// Fused: o = num * avg^alpha (staged to LDS, pipelined), Y = O @ B^T via MFMA,
// out[b] = sum_i o_i*(A_i + Y_i) + C. One x read from HBM; B-frags direct from L2.
template<bool USEBF>
__global__ __launch_bounds__(NTHR, 2)
void fused_kernel(const float* __restrict__ x, const float* __restrict__ A,
                  const float* __restrict__ Bf, const __bf16* __restrict__ Bb,
                  const float* __restrict__ Cp, const float* __restrict__ alpha,
                  float* __restrict__ out) {
    __shared__ __align__(16) __bf16 o_panel[BM * N_IN];   // 128 KB, XOR-swizzled
    __shared__ float rowsum[8][BM];                       // 2 KB

    const int t    = threadIdx.x;
    const int wave = t >> 6;
    const int lane = t & 63;
    const int lrow = lane & 15;   // frag row / col within 16
    const int lgrp = lane >> 4;   // k-group (0..3)
    const long blk_row = (long)blockIdx.x * BM;

    // staging role: 8 threads per row, each covers 4 consecutive k of a 32-chunk
    const int srow  = t >> 3;        // 0..63
    const int skoff = (t & 7) * 4;   // 0,4,...,28
    const float* xrow = x + (blk_row + srow) * (2 * N_IN);

    // ---- prologue: stage k-chunk 0 ----
    {
        int k = skoff;
        f32x4 sa  = *(const f32x4*)(xrow + k);
        f32x4 sn  = *(const f32x4*)(xrow + N_IN + k);
        f32x4 sal = *(const f32x4*)(alpha + k);
        bf16x4 w4;
        #pragma unroll
        for (int e = 0; e < 4; ++e) {
            float ov = sn[e] * __expf(sal[e] * __logf(sa[e]));
            w4[e] = (__bf16)ov;
        }
        int idx = srow * N_IN + ((k & ~7) ^ ((srow & 7) << 3)) + (k & 7);
        *(bf16x4*)&o_panel[idx] = w4;
    }
    __syncthreads();

    float rowpart[16];
    #pragma unroll
    for (int i = 0; i < 16; ++i) rowpart[i] = 0.f;

    #pragma unroll 1
    for (int pass = 0; pass < 2; ++pass) {
        const int colbase = pass * 512 + wave * 64;
        f32x4 acc[4][4];
        #pragma unroll
        for (int m = 0; m < 4; ++m)
            #pragma unroll
            for (int n = 0; n < 4; ++n)
                acc[m][n] = f32x4{0.f, 0.f, 0.f, 0.f};

        #pragma unroll 2
        for (int kc = 0; kc < 32; ++kc) {
            f32x4 sa, sn, sal;
            const bool staging = (pass == 0) && (kc + 1 < 32);
            if (staging) {   // issue next-chunk x loads early; latency hides under MFMA
                int k = (kc + 1) * 32 + skoff;
                sa  = *(const f32x4*)(xrow + k);
                sn  = *(const f32x4*)(xrow + N_IN + k);
                sal = *(const f32x4*)(alpha + k);
            }
            // A-frags from swizzled LDS o_panel: row = m*16+lrow, k = kc*32 + lgrp*8
            bf16x8 afr[4];
            #pragma unroll
            for (int m = 0; m < 4; ++m) {
                int r  = m * 16 + lrow;
                int kk = kc * 32 + lgrp * 8;
                afr[m] = *(const bf16x8*)&o_panel[r * N_IN + (kk ^ ((r & 7) << 3))];
            }
            // B-frags direct from global (L2-hot): col i, 8 consecutive k
            bf16x8 bfr[4];
            #pragma unroll
            for (int n = 0; n < 4; ++n) {
                int i  = colbase + n * 16 + lrow;
                int kk = kc * 32 + lgrp * 8;
                if constexpr (USEBF) {
                    bfr[n] = *(const bf16x8*)&Bb[(long)i * N_IN + kk];
                } else {
                    const float* p = Bf + (long)i * N_IN + kk;
                    f32x4 lo = *(const f32x4*)p;
                    f32x4 hi = *(const f32x4*)(p + 4);
                    #pragma unroll
                    for (int e = 0; e < 4; ++e) {
                        bfr[n][e]     = (__bf16)lo[e];
                        bfr[n][e + 4] = (__bf16)hi[e];
                    }
                }
            }
            #pragma unroll
            for (int m = 0; m < 4; ++m)
                #pragma unroll
                for (int n = 0; n < 4; ++n)
                    acc[m][n] = __builtin_amdgcn_mfma_f32_16x16x32_bf16(
                        afr[m], bfr[n], acc[m][n], 0, 0, 0);

            if (pass == 0) {
                if (staging) {   // pow + swizzled LDS write of chunk kc+1
                    int k = (kc + 1) * 32 + skoff;
                    bf16x4 w4;
                    #pragma unroll
                    for (int e = 0; e < 4; ++e) {
                        float ov = sn[e] * __expf(sal[e] * __logf(sa[e]));
                        w4[e] = (__bf16)ov;
                    }
                    int idx = srow * N_IN + ((k & ~7) ^ ((srow & 7) << 3)) + (k & 7);
                    *(bf16x4*)&o_panel[idx] = w4;
                }
                __syncthreads();   // chunk kc+1 visible for next iter
            }
        }

        // partial epilogue for this pass's 512 columns:
        // rowpart[r] += (Y[r][i] + A[i]) * o[r][i]
        #pragma unroll
        for (int n = 0; n < 4; ++n) {
            int i = colbase + n * 16 + lrow;
            float Ai = A[i];
            #pragma unroll
            for (int m = 0; m < 4; ++m) {
                #pragma unroll
                for (int j = 0; j < 4; ++j) {
                    int r = m * 16 + lgrp * 4 + j;    // C/D layout (m89-verified)
                    float y  = acc[m][n][j] + Ai;
                    float ov = (float)o_panel[r * N_IN + ((i & ~7) ^ ((r & 7) << 3)) + (i & 7)];
                    rowpart[m * 4 + j] += y * ov;
                }
            }
        }
    }

    // reduce over the 16 lanes (lane&15) that share the same rows
    #pragma unroll
    for (int d = 1; d < 16; d <<= 1) {
        #pragma unroll
        for (int i = 0; i < 16; ++i)
            rowpart[i] += __shfl_xor(rowpart[i], d);
    }
    if (lrow == 0) {
        #pragma unroll
        for (int m = 0; m < 4; ++m)
            #pragma unroll
            for (int j = 0; j < 4; ++j)
                rowsum[wave][m * 16 + lgrp * 4 + j] = rowpart[m * 4 + j];
    }
    __syncthreads();
    if (t < BM) {
        float s = Cp[0];
        #pragma unroll
        for (int w = 0; w < 8; ++w) s += rowsum[w][t];
        out[blk_row + t] = s;
    }
}

extern "C" void kernel_launch(void* const* d_in, const int* in_sizes, int n_in,
                              void* d_out, int out_size, void* d_ws, size_t ws_size,
                              hipStream_t stream) {
    const float* x     = (const float*)d_in[0];
    const float* A     = (const float*)d_in[1];
    const float* B     = (const float*)d_in[2];
    const float* C     = (const float*)d_in[3];
    const float* alpha = (const float*)d_in[4];
    float* out = (float*)d_out;

    int batch = in_sizes[0] / (2 * N_IN);   // 65536
    int grid  = batch / BM;                 // 1024

    bool useBf = (ws_size >= (size_t)(N_IN * N_IN * sizeof(__bf16)));
    if (useBf) {
        __bf16* Bb = (__bf16*)d_ws;
        int nvec = (N_IN * N_IN) / 4;
        convB_kernel<<<nvec / 256, 256, 0, stream>>>(B, Bb);
        fused_kernel<true><<<grid, NTHR, 0, stream>>>(x, A, nullptr, Bb, C, alpha, out);
    } else {
        fused_kernel<false><<<grid, NTHR, 0, stream>>>(x, A, B, nullptr, C, alpha, out);
    }
}

// Round 2
// 359.336 us; speedup vs baseline: 1.1313x; 1.1313x over previous
//
#include <hip/hip_runtime.h>
#include <hip/hip_bf16.h>

typedef __bf16 bf16x8 __attribute__((ext_vector_type(8)));
typedef __bf16 bf16x4 __attribute__((ext_vector_type(4)));
typedef float  f32x4  __attribute__((ext_vector_type(4)));

#define N_IN 1024
#define BM   64
#define NTHR 512

// Convert B (fp32, 1024x1024) to bf16 in workspace.
__global__ void convB_kernel(const float* __restrict__ B, __bf16* __restrict__ Bb) {
    int i = blockIdx.x * blockDim.x + threadIdx.x;
    f32x4 v = ((const f32x4*)B)[i];
    bf16x4 o;
    o[0] = (__bf16)v[0]; o[1] = (__bf16)v[1]; o[2] = (__bf16)v[2]; o[3] = (__bf16)v[3];
    ((bf16x4*)Bb)[i] = o;
}

// Fused: o = num * avg^alpha (staged to LDS, 8-chunk-deep pipeline, 4 barriers),
// Y = O @ B^T via MFMA with BOTH column-halves' acc live, then
// out[b] = sum_i o_i*(A_i + Y_i) + C.
template<bool USEBF>
__global__ __launch_bounds__(NTHR, 2)
void fused_kernel(const float* __restrict__ x, const float* __restrict__ A,
                  const float* __restrict__ Bf, const __bf16* __restrict__ Bb,
                  const float* __restrict__ Cp, const float* __restrict__ alpha,
                  float* __restrict__ out) {
    __shared__ __align__(16) __bf16 o_panel[BM * N_IN];   // 128 KB, XOR-swizzled
    __shared__ float rowsum[8][BM];                       // 2 KB

    const int t    = threadIdx.x;
    const int wave = t >> 6;
    const int lane = t & 63;
    const int lrow = lane & 15;   // frag row / col within 16
    const int lgrp = lane >> 4;   // k-group (0..3)
    const long blk_row = (long)blockIdx.x * BM;

    // staging role: 8 threads per row, 4 consecutive k each, 32-k chunks
    const int srow  = t >> 3;        // 0..63
    const int skoff = (t & 7) * 4;   // 0,4,...,28
    const float* xrow = x + (blk_row + srow) * (2 * N_IN);

    // ---- prologue: stage chunks 0..7 (k 0..255) ----
    #pragma unroll
    for (int c = 0; c < 8; ++c) {
        int k = c * 32 + skoff;
        f32x4 sa  = *(const f32x4*)(xrow + k);
        f32x4 sn  = *(const f32x4*)(xrow + N_IN + k);
        f32x4 sal = *(const f32x4*)(alpha + k);
        bf16x4 w4;
        #pragma unroll
        for (int e = 0; e < 4; ++e)
            w4[e] = (__bf16)(sn[e] * __expf(sal[e] * __logf(sa[e])));
        *(bf16x4*)&o_panel[srow * N_IN + ((k & ~7) ^ ((srow & 7) << 3)) + (k & 7)] = w4;
    }
    __syncthreads();

    f32x4 acc[2][4][4];
    #pragma unroll
    for (int h = 0; h < 2; ++h)
        #pragma unroll
        for (int m = 0; m < 4; ++m)
            #pragma unroll
            for (int n = 0; n < 4; ++n)
                acc[h][m][n] = f32x4{0.f, 0.f, 0.f, 0.f};

    // ---- main loop: 4 quarters x 8 kc; stage chunk kc+8 during iter kc ----
    #pragma unroll 1
    for (int q = 0; q < 4; ++q) {
        #pragma unroll
        for (int kq = 0; kq < 8; ++kq) {
            const int kc = q * 8 + kq;
            const bool staging = (q < 3);
            f32x4 sa, sn, sal;
            if (staging) {   // issue loads early; latency hides under MFMA
                int k = (kc + 8) * 32 + skoff;
                sa  = *(const f32x4*)(xrow + k);
                sn  = *(const f32x4*)(xrow + N_IN + k);
                sal = *(const f32x4*)(alpha + k);
            }
            const int kk = kc * 32 + lgrp * 8;
            // A-frags from swizzled LDS (shared by both column halves)
            bf16x8 afr[4];
            #pragma unroll
            for (int m = 0; m < 4; ++m) {
                int r = m * 16 + lrow;
                afr[m] = *(const bf16x8*)&o_panel[r * N_IN + (kk ^ ((r & 7) << 3))];
            }
            // B-frags direct from L2 for both column halves
            bf16x8 bfr[2][4];
            #pragma unroll
            for (int h = 0; h < 2; ++h)
                #pragma unroll
                for (int n = 0; n < 4; ++n) {
                    int i = h * 512 + wave * 64 + n * 16 + lrow;
                    if constexpr (USEBF) {
                        bfr[h][n] = *(const bf16x8*)&Bb[(long)i * N_IN + kk];
                    } else {
                        const float* p = Bf + (long)i * N_IN + kk;
                        f32x4 lo = *(const f32x4*)p;
                        f32x4 hi = *(const f32x4*)(p + 4);
                        #pragma unroll
                        for (int e = 0; e < 4; ++e) {
                            bfr[h][n][e]     = (__bf16)lo[e];
                            bfr[h][n][e + 4] = (__bf16)hi[e];
                        }
                    }
                }
            #pragma unroll
            for (int h = 0; h < 2; ++h)
                #pragma unroll
                for (int m = 0; m < 4; ++m)
                    #pragma unroll
                    for (int n = 0; n < 4; ++n)
                        acc[h][m][n] = __builtin_amdgcn_mfma_f32_16x16x32_bf16(
                            afr[m], bfr[h][n], acc[h][m][n], 0, 0, 0);
            if (staging) {   // pow + swizzled LDS write after the MFMA cluster
                int k = (kc + 8) * 32 + skoff;
                bf16x4 w4;
                #pragma unroll
                for (int e = 0; e < 4; ++e)
                    w4[e] = (__bf16)(sn[e] * __expf(sal[e] * __logf(sa[e])));
                *(bf16x4*)&o_panel[srow * N_IN + ((k & ~7) ^ ((srow & 7) << 3)) + (k & 7)] = w4;
            }
        }
        __syncthreads();   // quarter boundary: staged chunks visible
    }

    // ---- epilogue: rowpart[r] += (Y[r][i] + A[i]) * o[r][i] ----
    float rowpart[16];
    #pragma unroll
    for (int i = 0; i < 16; ++i) rowpart[i] = 0.f;
    #pragma unroll
    for (int h = 0; h < 2; ++h)
        #pragma unroll
        for (int n = 0; n < 4; ++n) {
            int i = h * 512 + wave * 64 + n * 16 + lrow;
            float Ai = A[i];
            #pragma unroll
            for (int m = 0; m < 4; ++m)
                #pragma unroll
                for (int j = 0; j < 4; ++j) {
                    int r = m * 16 + lgrp * 4 + j;    // C/D layout (m89-verified)
                    float y  = acc[h][m][n][j] + Ai;
                    float ov = (float)o_panel[r * N_IN + ((i & ~7) ^ ((r & 7) << 3)) + (i & 7)];
                    rowpart[m * 4 + j] += y * ov;
                }
        }

    // reduce over the 16 lanes sharing the same rows
    #pragma unroll
    for (int d = 1; d < 16; d <<= 1) {
        #pragma unroll
        for (int i = 0; i < 16; ++i)
            rowpart[i] += __shfl_xor(rowpart[i], d);
    }
    if (lrow == 0) {
        #pragma unroll
        for (int m = 0; m < 4; ++m)
            #pragma unroll
            for (int j = 0; j < 4; ++j)
                rowsum[wave][m * 16 + lgrp * 4 + j] = rowpart[m * 4 + j];
    }
    __syncthreads();
    if (t < BM) {
        float s = Cp[0];
        #pragma unroll
        for (int w = 0; w < 8; ++w) s += rowsum[w][t];
        out[blk_row + t] = s;
    }
}

extern "C" void kernel_launch(void* const* d_in, const int* in_sizes, int n_in,
                              void* d_out, int out_size, void* d_ws, size_t ws_size,
                              hipStream_t stream) {
    const float* x     = (const float*)d_in[0];
    const float* A     = (const float*)d_in[1];
    const float* B     = (const float*)d_in[2];
    const float* C     = (const float*)d_in[3];
    const float* alpha = (const float*)d_in[4];
    float* out = (float*)d_out;

    int batch = in_sizes[0] / (2 * N_IN);   // 65536
    int grid  = batch / BM;                 // 1024

    bool useBf = (ws_size >= (size_t)(N_IN * N_IN * sizeof(__bf16)));
    if (useBf) {
        __bf16* Bb = (__bf16*)d_ws;
        int nvec = (N_IN * N_IN) / 4;
        convB_kernel<<<nvec / 256, 256, 0, stream>>>(B, Bb);
        fused_kernel<true><<<grid, NTHR, 0, stream>>>(x, A, nullptr, Bb, C, alpha, out);
    } else {
        fused_kernel<false><<<grid, NTHR, 0, stream>>>(x, A, B, nullptr, C, alpha, out);
    }
}